// Round 2
// 1132.430 us; speedup vs baseline: 1.2861x; 1.2861x over previous
//
#include <hip/hip_runtime.h>
#include <hip/hip_bf16.h>

namespace {

constexpr int Md = 512, Cd = 256, Bd = 8, Td = 32;
constexpr float kLam = 0.05f, kRho = 0.9f, kDlr = 0.03f;
constexpr float kEps = 1e-12f, kLnEps = 1e-5f;

typedef __attribute__((ext_vector_type(8))) short short8;
typedef __attribute__((ext_vector_type(4))) float float4v;

// ---- workspace layout (bytes) ----
constexpr size_t SZ_WC2   = (size_t)Cd * Cd * Md * 2;      // bf16 Wc2[c'][c][m]
constexpr size_t SZ_CU    = (size_t)Td * Bd * Cd * Md * 2; // bf16 CU[t*8+b][c][m]
constexpr size_t SZ_D     = (size_t)Bd * Cd * Md * 4;      // f32 D[b][c][m]
constexpr size_t SZ_S     = SZ_D;                          // f32 S[b][c][m]
constexpr size_t SZ_WCUT  = (size_t)Md * Cd * 4;
constexpr size_t SZ_WCCGT = (size_t)Cd * Cd * 4;           // f32 WccGT[i][c']
constexpr size_t SZ_LU    = (size_t)Td * Bd * Cd * 4;      // f32 Lu[t*8+b][c']
constexpr size_t SZ_UB    = (size_t)Td * Bd * Md * 2;      // bf16 Ub[n][d]
constexpr size_t SZ_CY    = (size_t)Bd * Cd * 4;           // f32 [b][c]

constexpr size_t OFF_WC2   = 0;
constexpr size_t OFF_CU    = OFF_WC2 + SZ_WC2;
constexpr size_t OFF_D0    = OFF_CU + SZ_CU;
constexpr size_t OFF_D1    = OFF_D0 + SZ_D;
constexpr size_t OFF_S     = OFF_D1 + SZ_D;
constexpr size_t OFF_WCUT  = OFF_S + SZ_S;
constexpr size_t OFF_WCCGT = OFF_WCUT + SZ_WCUT;
constexpr size_t OFF_GW    = OFF_WCCGT + SZ_WCCGT;
constexpr size_t OFF_BW    = OFF_GW + 1024;
constexpr size_t OFF_LU    = OFF_BW + 1024;
constexpr size_t OFF_UB    = OFF_LU + SZ_LU;
constexpr size_t OFF_C0    = OFF_UB + SZ_UB;
constexpr size_t OFF_C1    = OFF_C0 + SZ_CY;
constexpr size_t OFF_Y0    = OFF_C1 + SZ_CY;
constexpr size_t OFF_Y1    = OFF_Y0 + SZ_CY;

__device__ __forceinline__ unsigned short f2bf(float x) {
  __hip_bfloat16 h = __float2bfloat16(x);
  return *reinterpret_cast<unsigned short*>(&h);
}

__device__ __forceinline__ float bf2float(unsigned short x) {
  unsigned int uu = ((unsigned int)x) << 16;
  return __uint_as_float(uu);
}

// ---- 256-thread block reductions (4 waves) ----
__device__ __forceinline__ float block_reduce_sum(float v, float* sbuf) {
  const int tid = threadIdx.x;
  #pragma unroll
  for (int o = 32; o > 0; o >>= 1) v += __shfl_down(v, o, 64);
  __syncthreads();
  if ((tid & 63) == 0) sbuf[tid >> 6] = v;
  __syncthreads();
  return sbuf[0] + sbuf[1] + sbuf[2] + sbuf[3];
}

__device__ __forceinline__ float2 block_reduce_sum2(float a, float b, float* sbuf) {
  const int tid = threadIdx.x;
  #pragma unroll
  for (int o = 32; o > 0; o >>= 1) {
    a += __shfl_down(a, o, 64);
    b += __shfl_down(b, o, 64);
  }
  __syncthreads();
  if ((tid & 63) == 0) { sbuf[tid >> 6] = a; sbuf[4 + (tid >> 6)] = b; }
  __syncthreads();
  return make_float2(sbuf[0] + sbuf[1] + sbuf[2] + sbuf[3],
                     sbuf[4] + sbuf[5] + sbuf[6] + sbuf[7]);
}

__device__ __forceinline__ void red2(float& a, float& b, float* redf) {
  const int tid = threadIdx.x;
  #pragma unroll
  for (int o = 32; o > 0; o >>= 1) {
    a += __shfl_down(a, o, 64);
    b += __shfl_down(b, o, 64);
  }
  __syncthreads();
  if ((tid & 63) == 0) { int w = tid >> 6; redf[w * 2] = a; redf[w * 2 + 1] = b; }
  __syncthreads();
  a = redf[0] + redf[2] + redf[4] + redf[6];
  b = redf[1] + redf[3] + redf[5] + redf[7];
}

__device__ __forceinline__ void red4(float& a, float& b, float& c, float& d,
                                     float* redf) {
  const int tid = threadIdx.x;
  #pragma unroll
  for (int o = 32; o > 0; o >>= 1) {
    a += __shfl_down(a, o, 64); b += __shfl_down(b, o, 64);
    c += __shfl_down(c, o, 64); d += __shfl_down(d, o, 64);
  }
  __syncthreads();
  if ((tid & 63) == 0) {
    int w = tid >> 6;
    redf[w * 4] = a; redf[w * 4 + 1] = b; redf[w * 4 + 2] = c; redf[w * 4 + 3] = d;
  }
  __syncthreads();
  a = redf[0] + redf[4] + redf[8]  + redf[12];
  b = redf[1] + redf[5] + redf[9]  + redf[13];
  c = redf[2] + redf[6] + redf[10] + redf[14];
  d = redf[3] + redf[7] + redf[11] + redf[15];
}

// ---- init: D0 -> Db1, zero S, cst0, Yg0 ----
__global__ __launch_bounds__(256) void k_init(const float* __restrict__ base,
                                              float* __restrict__ D1,
                                              float* __restrict__ S,
                                              float* __restrict__ c0g,
                                              float* __restrict__ y0g) {
  __shared__ float red[8];
  const int tid = threadIdx.x;
  const int c = blockIdx.x;
  float b0 = base[(size_t)tid * Cd + c];
  float b1 = base[(size_t)(tid + 256) * Cd + c];
  float ss = block_reduce_sum(b0 * b0 + b1 * b1, red);
  float rinv = 1.0f / fmaxf(sqrtf(ss), kEps);
  #pragma unroll
  for (int bb = 0; bb < Bd; ++bb) {
    size_t off = ((size_t)(bb * Cd + c)) * Md;
    D1[off + tid] = b0 * rinv;
    D1[off + tid + 256] = b1 * rinv;
  }
  size_t s0 = (size_t)c * 4096;
  #pragma unroll
  for (int k = 0; k < 16; ++k) S[s0 + k * 256 + tid] = 0.0f;
  if (c < Bd) { c0g[c * Cd + tid] = 0.0f; y0g[c * Cd + tid] = 0.0f; }
}

// ---- transpose W_cu (C,M) into WcuT[d][c] ----
__global__ __launch_bounds__(256) void k_transpose_wcu(const float* __restrict__ Wcu,
                                                       float* __restrict__ WcuT) {
  int g = blockIdx.x * 256 + threadIdx.x;  // g < M*C
  int d = g >> 8, c = g & 255;
  WcuT[g] = Wcu[(size_t)c * Md + d];
}

// ---- WccGT[i][c'] = lcg[i]*Wcc[c'][i]; GW[c']=sum_i g_i Wcc[c',i]; BW sim. ----
__global__ __launch_bounds__(256) void k_prep_wcc(const float* __restrict__ Wcc,
                                                  const float* __restrict__ lcg,
                                                  const float* __restrict__ lcb,
                                                  float* __restrict__ WccGT,
                                                  float* __restrict__ GW,
                                                  float* __restrict__ BW) {
  __shared__ float red[8];
  const int cp = blockIdx.x;
  const int tid = threadIdx.x;
  float wv = Wcc[(size_t)cp * Cd + tid];
  float g = lcg[tid], bb = lcb[tid];
  WccGT[(size_t)tid * Cd + cp] = g * wv;
  float2 ss = block_reduce_sum2(g * wv, bb * wv, red);
  if (tid == 0) { GW[cp] = ss.x; BW[cp] = ss.y; }
}

// ---- Lu[n][c'] = LN(u_n) . WcuT[:,c'] ----
__global__ __launch_bounds__(256) void k_prep_lu(const float* __restrict__ u,
                                                 const float* __restrict__ WcuT,
                                                 const float* __restrict__ lug,
                                                 const float* __restrict__ lub,
                                                 float* __restrict__ Lu) {
  __shared__ float ln[512];
  __shared__ float red[8];
  const int n = blockIdx.x;           // n = t*8+b
  const int t = n >> 3, b = n & 7;
  const int tid = threadIdx.x;
  const float* up = u + ((size_t)(b * Td + t)) * Md;
  float u0 = up[tid], u1 = up[tid + 256];
  float2 ss = block_reduce_sum2(u0 + u1, u0 * u0 + u1 * u1, red);
  float mu = ss.x * (1.0f / 512.0f);
  float var = ss.y * (1.0f / 512.0f) - mu * mu;
  float rsu = rsqrtf(var + kLnEps);
  ln[tid] = (u0 - mu) * rsu * lug[tid] + lub[tid];
  ln[tid + 256] = (u1 - mu) * rsu * lug[tid + 256] + lub[tid + 256];
  __syncthreads();
  float acc = 0.0f;
  #pragma unroll 8
  for (int i = 0; i < 512; ++i) acc = fmaf(ln[i], WcuT[(size_t)i * Cd + tid], acc);
  Lu[(size_t)n * Cd + tid] = acc;
}

// ---- build Wc2[c'][c][m] = W_cand_c[(m*C+c)][c'] as bf16 ----
__global__ __launch_bounds__(256) void k_build_wc2(const float* __restrict__ Wc,
                                                   __hip_bfloat16* __restrict__ Wc2) {
  __shared__ float tile[64][65];
  const int tid = threadIdx.x;
  const int bid = blockIdx.x;
  const int ct = bid & 3;
  const int mt = (bid >> 2) & 7;
  const int c = bid >> 5;
  const int c0p = ct * 64, m0 = mt * 64;
  const int x = tid & 63, y = tid >> 6;
  #pragma unroll
  for (int i = 0; i < 16; ++i) {
    int mm = m0 + y + i * 4;
    tile[y + i * 4][x] = Wc[((size_t)(mm * Cd + c)) * Cd + c0p + x];
  }
  __syncthreads();
  #pragma unroll
  for (int i = 0; i < 16; ++i) {
    int cp = c0p + y + i * 4;
    Wc2[((size_t)(cp * Cd + c)) * Md + m0 + x] = __float2bfloat16(tile[x][y + i * 4]);
  }
}

// ---- convert u -> bf16 Ub[n][d], n = t*8+b ----
__global__ __launch_bounds__(256) void k_prep_u(const float* __restrict__ u,
                                                __hip_bfloat16* __restrict__ Ub) {
  const int n = blockIdx.x;
  const int t = n >> 3, b = n & 7;
  const int tid = threadIdx.x;
  const float* src = u + ((size_t)(b * Td + t)) * Md;
  __hip_bfloat16* dst = Ub + (size_t)n * Md;
  dst[tid] = __float2bfloat16(src[tid]);
  dst[tid + 256] = __float2bfloat16(src[tid + 256]);
}

// ---- MFMA precompute: CU[n][c][m] = Ub[n]·Wu_row(m*C+c) + b_u + b_c ----
__global__ __launch_bounds__(256) void k_build_cu(const float* __restrict__ Wu,
                                                  const float* __restrict__ bu,
                                                  const float* __restrict__ bc,
                                                  const __hip_bfloat16* __restrict__ Ub,
                                                  __hip_bfloat16* __restrict__ CU) {
  __shared__ unsigned short smem[256 * 72];  // Bs: stride 40; Ct: stride 72
  const int tid = threadIdx.x;
  const int c = blockIdx.x >> 3;
  const int mt = blockIdx.x & 7;
  const int w = tid >> 6;
  const int lane = tid & 63;
  const int l15 = lane & 15;
  const int quad = lane >> 4;

  float4v acc[16];
  #pragma unroll
  for (int j = 0; j < 16; ++j) acc[j] = (float4v){0.f, 0.f, 0.f, 0.f};

  const int mrow = mt * 64 + w * 16 + l15;
  const float* Arow = Wu + ((size_t)mrow * Cd + c) * Md;
  const unsigned short* ubp = (const unsigned short*)Ub + (size_t)tid * Md;

  for (int ch = 0; ch < 16; ++ch) {
    const int d0 = ch * 32;
    short8 s0 = *(const short8*)(ubp + d0);
    short8 s1 = *(const short8*)(ubp + d0 + 8);
    short8 s2 = *(const short8*)(ubp + d0 + 16);
    short8 s3 = *(const short8*)(ubp + d0 + 24);
    __syncthreads();
    *(short8*)&smem[tid * 40 + 0]  = s0;
    *(short8*)&smem[tid * 40 + 8]  = s1;
    *(short8*)&smem[tid * 40 + 16] = s2;
    *(short8*)&smem[tid * 40 + 24] = s3;
    float4 a0 = *(const float4*)(Arow + d0 + quad * 8);
    float4 a1 = *(const float4*)(Arow + d0 + quad * 8 + 4);
    short8 af;
    af[0] = (short)f2bf(a0.x); af[1] = (short)f2bf(a0.y);
    af[2] = (short)f2bf(a0.z); af[3] = (short)f2bf(a0.w);
    af[4] = (short)f2bf(a1.x); af[5] = (short)f2bf(a1.y);
    af[6] = (short)f2bf(a1.z); af[7] = (short)f2bf(a1.w);
    __syncthreads();
    #pragma unroll
    for (int j = 0; j < 16; ++j) {
      short8 bf = *(const short8*)&smem[(j * 16 + l15) * 40 + quad * 8];
      acc[j] = __builtin_amdgcn_mfma_f32_16x16x32_bf16(af, bf, acc[j], 0, 0, 0);
    }
  }

  float bias[4];
  #pragma unroll
  for (int r2 = 0; r2 < 4; ++r2) {
    int m = mt * 64 + w * 16 + quad * 4 + r2;
    bias[r2] = bu[(size_t)m * Cd + c] + bc[(size_t)m * Cd + c];
  }
  __syncthreads();
  #pragma unroll
  for (int j = 0; j < 16; ++j) {
    int tok = j * 16 + l15;
    int mlb = w * 16 + quad * 4;
    uint2 pk;
    pk.x = (unsigned)f2bf(acc[j][0] + bias[0]) |
           ((unsigned)f2bf(acc[j][1] + bias[1]) << 16);
    pk.y = (unsigned)f2bf(acc[j][2] + bias[2]) |
           ((unsigned)f2bf(acc[j][3] + bias[3]) << 16);
    *(uint2*)&smem[tok * 72 + mlb] = pk;
  }
  __syncthreads();
  #pragma unroll
  for (int rr = 0; rr < 8; ++rr) {
    int tok = (tid >> 3) + rr * 32;
    int ml0 = (tid & 7) * 8;
    short8 vv = *(const short8*)&smem[tok * 72 + ml0];
    *(short8*)((unsigned short*)CU + ((size_t)tok * Cd + c) * Md + mt * 64 + ml0) = vv;
  }
}

// ---- per-step kernel: 1024 blocks x 256 thr; everything for one step ----
// Block blk: b = blk>>7, j = blk&127; owns dict columns c0=2j, c1=2j+1.
// Small phase (LN-c, logits, top-8, c/Y update, gate) replicated per block.
// Cross-step state in global: D (dbl-buf), S, c (dbl-buf), Y (dbl-buf).
__global__ __launch_bounds__(256, 4) void k_step(
    const float* __restrict__ u, const float* __restrict__ valid,
    const float* __restrict__ Wg, const float* __restrict__ bg,
    const float* __restrict__ Lu, const float* __restrict__ GW,
    const float* __restrict__ BW, const float* __restrict__ WccGT,
    const unsigned short* __restrict__ Wc2, const unsigned short* __restrict__ CUb,
    const float* __restrict__ Dprev, float* __restrict__ Dcur,
    float* __restrict__ Sg,
    const float* __restrict__ cprev, float* __restrict__ ccur,
    const float* __restrict__ Yprev, float* __restrict__ Ycur,
    float* __restrict__ out, int t) {
  __shared__ float cs[256];
  __shared__ float scs[256];
  __shared__ float shs[256];
  __shared__ float zred[256];
  __shared__ float redf[16];
  __shared__ float aval_s[8];
  __shared__ int aidx_s[8];

  const int tid = threadIdx.x;
  const int blk = blockIdx.x;
  const int b = blk >> 7;
  const int j = blk & 127;
  const int c0 = 2 * j, c1 = 2 * j + 1;

  const float cv = cprev[b * Cd + tid];
  cs[tid] = cv;
  float Yv = Yprev[b * Cd + tid];
  __syncthreads();

  // ---- z finalize for step t-1 (16 designated blocks per b, 32 m each) ----
  if (j < 16 && t > 0) {
    const int ml = tid & 31, cgp = tid >> 5;
    const int m = j * 32 + ml;
    float acc = 0.f;
    #pragma unroll 4
    for (int i = 0; i < 32; ++i) {
      int cc = cgp * 32 + i;
      acc = fmaf(Dprev[((size_t)(b * Cd + cc)) * Md + m], cs[cc], acc);
    }
    zred[tid] = acc;
    __syncthreads();
    if (tid < 32) {
      float s = 0.f;
      #pragma unroll
      for (int g2 = 0; g2 < 8; ++g2) s += zred[g2 * 32 + tid];
      out[((size_t)(b * Td + (t - 1))) * Md + j * 32 + tid] = s;
    }
  }

  const float v = valid[b * Td + t];
  const float lam_b = v * kRho + (1.f - v);   // c_t = lam*c + mu*a
  const float mu_b  = v * (1.f - kRho);

  // ---- LN stats of c_prev ----
  float sa = cv, sb = cv * cv;
  red2(sa, sb, redf);
  float muc = sa * (1.f / 256.f);
  float rsc = rsqrtf(sb * (1.f / 256.f) - muc * muc + kLnEps);

  // ---- logits + shrink ----
  float lg = Lu[((size_t)(t * Bd + b)) * Cd + tid] + rsc * (Yv - muc * GW[tid]) + BW[tid];
  float sv = fmaxf(fabsf(lg) - kLam, 0.f);
  scs[tid] = sv;
  shs[tid] = (lg >= 0.f) ? sv : -sv;
  __syncthreads();

  // ---- top-8 (wave 0; value desc, index asc tie-break) ----
  if (tid < 64) {
    float v4[4]; int i4[4];
    #pragma unroll
    for (int k = 0; k < 4; ++k) { i4[k] = tid * 4 + k; v4[k] = scs[tid * 4 + k]; }
    for (int i = 0; i < 8; ++i) {
      float bv = v4[0]; int bi = i4[0];
      #pragma unroll
      for (int k = 1; k < 4; ++k)
        if (v4[k] > bv || (v4[k] == bv && i4[k] < bi)) { bv = v4[k]; bi = i4[k]; }
      #pragma unroll
      for (int o = 32; o > 0; o >>= 1) {
        float ov = __shfl_xor(bv, o, 64);
        int oi = __shfl_xor(bi, o, 64);
        if (ov > bv || (ov == bv && oi < bi)) { bv = ov; bi = oi; }
      }
      if (tid == 0) { aidx_s[i] = bi; aval_s[i] = shs[bi]; }
      if ((bi >> 2) == tid) v4[bi & 3] = -1.0f;
    }
  }
  __syncthreads();

  // ---- c update + incremental Y update ----
  float a_t = 0.f;
  #pragma unroll
  for (int k = 0; k < 8; ++k) if (aidx_s[k] == tid) a_t = aval_s[k];
  float ct = lam_b * cv + mu_b * a_t;
  float yn = lam_b * Yv;
  #pragma unroll
  for (int k = 0; k < 8; ++k)
    yn = fmaf(mu_b * aval_s[k], WccGT[(size_t)aidx_s[k] * Cd + tid], yn);
  if (j == 0) { ccur[b * Cd + tid] = ct; Ycur[b * Cd + tid] = yn; }

  // ---- u_hat, r, err, gate (replicated) ----
  float2 uu = *(const float2*)&u[((size_t)(b * Td + t)) * Md + 2 * tid];
  float uh0 = 0.f, uh1 = 0.f;
  #pragma unroll
  for (int k = 0; k < 8; ++k) {
    float2 dp = *(const float2*)&Dprev[((size_t)(b * Cd + aidx_s[k])) * Md + 2 * tid];
    uh0 = fmaf(aval_s[k], dp.x, uh0);
    uh1 = fmaf(aval_s[k], dp.y, uh1);
  }
  float r0 = uu.x - uh0, r1 = uu.y - uh1;
  float e2 = r0 * r0 + r1 * r1;
  float gp = Wg[2 * tid] * uu.x + Wg[2 * tid + 1] * uu.y + Wg[512 + tid] * ct;
  red2(e2, gp, redf);
  float gate = 1.f / (1.f + expf(-(gp + Wg[768] * sqrtf(e2) + bg[0])));

  // ---- dictionary update for this block's 2 columns ----
  float a0 = 0.f, a1 = 0.f;
  #pragma unroll
  for (int k = 0; k < 8; ++k) {
    if (aidx_s[k] == c0) a0 = aval_s[k];
    if (aidx_s[k] == c1) a1 = aval_s[k];
  }
  float w0x = 0.f, w0y = 0.f, w1x = 0.f, w1y = 0.f;
  #pragma unroll
  for (int k = 0; k < 8; ++k) {
    const unsigned short* wr = Wc2 + ((size_t)aidx_s[k] * Cd) * Md;
    float av = aval_s[k];
    ushort2 q0 = *(const ushort2*)(wr + (size_t)c0 * Md + 2 * tid);
    ushort2 q1 = *(const ushort2*)(wr + (size_t)c1 * Md + 2 * tid);
    w0x = fmaf(av, bf2float(q0.x), w0x);
    w0y = fmaf(av, bf2float(q0.y), w0y);
    w1x = fmaf(av, bf2float(q1.x), w1x);
    w1y = fmaf(av, bf2float(q1.y), w1y);
  }
  float2 s0 = *(const float2*)&Sg[((size_t)(b * Cd + c0)) * Md + 2 * tid];
  float2 s1 = *(const float2*)&Sg[((size_t)(b * Cd + c1)) * Md + 2 * tid];
  float s0x = lam_b * s0.x + mu_b * w0x;
  float s0y = lam_b * s0.y + mu_b * w0y;
  float s1x = lam_b * s1.x + mu_b * w1x;
  float s1y = lam_b * s1.y + mu_b * w1y;
  *(float2*)&Sg[((size_t)(b * Cd + c0)) * Md + 2 * tid] = make_float2(s0x, s0y);
  *(float2*)&Sg[((size_t)(b * Cd + c1)) * Md + 2 * tid] = make_float2(s1x, s1y);

  const unsigned short* cup = CUb + ((size_t)((t * Bd + b) * Cd)) * Md;
  ushort2 qc0 = *(const ushort2*)(cup + (size_t)c0 * Md + 2 * tid);
  ushort2 qc1 = *(const ushort2*)(cup + (size_t)c1 * Md + 2 * tid);
  float cn0x = bf2float(qc0.x) + s0x, cn0y = bf2float(qc0.y) + s0y;
  float cn1x = bf2float(qc1.x) + s1x, cn1y = bf2float(qc1.y) + s1y;

  float2 dp0 = *(const float2*)&Dprev[((size_t)(b * Cd + c0)) * Md + 2 * tid];
  float2 dp1 = *(const float2*)&Dprev[((size_t)(b * Cd + c1)) * Md + 2 * tid];
  float dl0x = fmaf(kDlr * a0, r0, dp0.x), dl0y = fmaf(kDlr * a0, r1, dp0.y);
  float dl1x = fmaf(kDlr * a1, r0, dp1.x), dl1y = fmaf(kDlr * a1, r1, dp1.y);

  float na = cn0x * cn0x + cn0y * cn0y;
  float nb = dl0x * dl0x + dl0y * dl0y;
  float nc = cn1x * cn1x + cn1y * cn1y;
  float nd = dl1x * dl1x + dl1y * dl1y;
  red4(na, nb, nc, nd, redf);
  float ric0 = 1.f / fmaxf(sqrtf(na), kEps);
  float rid0 = 1.f / fmaxf(sqrtf(nb), kEps);
  float ric1 = 1.f / fmaxf(sqrtf(nc), kEps);
  float rid1 = 1.f / fmaxf(sqrtf(nd), kEps);

  float og = 1.f - gate;
  float e0x = og * dl0x * rid0 + gate * cn0x * ric0;
  float e0y = og * dl0y * rid0 + gate * cn0y * ric0;
  float e1x = og * dl1x * rid1 + gate * cn1x * ric1;
  float e1y = og * dl1y * rid1 + gate * cn1y * ric1;

  float q0s = e0x * e0x + e0y * e0y;
  float q1s = e1x * e1x + e1y * e1y;
  red2(q0s, q1s, redf);
  float rie0 = 1.f / fmaxf(sqrtf(q0s), kEps);
  float rie1 = 1.f / fmaxf(sqrtf(q1s), kEps);

  float ov = 1.f - v;
  float dn0x = v * (e0x * rie0) + ov * dp0.x;
  float dn0y = v * (e0y * rie0) + ov * dp0.y;
  float dn1x = v * (e1x * rie1) + ov * dp1.x;
  float dn1y = v * (e1y * rie1) + ov * dp1.y;

  *(float2*)&Dcur[((size_t)(b * Cd + c0)) * Md + 2 * tid] = make_float2(dn0x, dn0y);
  *(float2*)&Dcur[((size_t)(b * Cd + c1)) * Md + 2 * tid] = make_float2(dn1x, dn1y);
}

// ---- final z for t = T-1: 128 blocks = (b, j) ----
__global__ __launch_bounds__(256) void k_zfinal(const float* __restrict__ Dlast,
                                                const float* __restrict__ clast,
                                                float* __restrict__ out) {
  __shared__ float cs[256];
  __shared__ float zred[256];
  const int tid = threadIdx.x;
  const int b = blockIdx.x >> 4;
  const int j = blockIdx.x & 15;
  cs[tid] = clast[b * Cd + tid];
  __syncthreads();
  const int ml = tid & 31, cgp = tid >> 5;
  const int m = j * 32 + ml;
  float acc = 0.f;
  #pragma unroll 4
  for (int i = 0; i < 32; ++i) {
    int cc = cgp * 32 + i;
    acc = fmaf(Dlast[((size_t)(b * Cd + cc)) * Md + m], cs[cc], acc);
  }
  zred[tid] = acc;
  __syncthreads();
  if (tid < 32) {
    float s = 0.f;
    #pragma unroll
    for (int g2 = 0; g2 < 8; ++g2) s += zred[g2 * 32 + tid];
    out[((size_t)(b * Td + (Td - 1))) * Md + j * 32 + tid] = s;
  }
}

}  // namespace

extern "C" void kernel_launch(void* const* d_in, const int* in_sizes, int n_in,
                              void* d_out, int out_size, void* d_ws, size_t ws_size,
                              hipStream_t stream) {
  (void)in_sizes; (void)n_in; (void)out_size; (void)ws_size;
  const float* u     = (const float*)d_in[0];
  const float* valid = (const float*)d_in[1];
  const float* base  = (const float*)d_in[2];
  const float* Wcu   = (const float*)d_in[3];
  const float* Wcc   = (const float*)d_in[4];
  const float* Wu    = (const float*)d_in[5];
  const float* bu    = (const float*)d_in[6];
  const float* Wc    = (const float*)d_in[7];
  const float* bc    = (const float*)d_in[8];
  const float* Wg    = (const float*)d_in[9];
  const float* bg    = (const float*)d_in[10];
  const float* lug   = (const float*)d_in[11];
  const float* lub   = (const float*)d_in[12];
  const float* lcg   = (const float*)d_in[13];
  const float* lcb   = (const float*)d_in[14];
  float* out = (float*)d_out;
  char* ws = (char*)d_ws;

  __hip_bfloat16* Wc2 = (__hip_bfloat16*)(ws + OFF_WC2);
  __hip_bfloat16* CU  = (__hip_bfloat16*)(ws + OFF_CU);
  float* Db0   = (float*)(ws + OFF_D0);
  float* Db1   = (float*)(ws + OFF_D1);
  float* Sg    = (float*)(ws + OFF_S);
  float* WcuT  = (float*)(ws + OFF_WCUT);
  float* WccGT = (float*)(ws + OFF_WCCGT);
  float* GW    = (float*)(ws + OFF_GW);
  float* BW    = (float*)(ws + OFF_BW);
  float* Lu    = (float*)(ws + OFF_LU);
  __hip_bfloat16* Ub = (__hip_bfloat16*)(ws + OFF_UB);
  float* cst0  = (float*)(ws + OFF_C0);
  float* cst1  = (float*)(ws + OFF_C1);
  float* Yg0   = (float*)(ws + OFF_Y0);
  float* Yg1   = (float*)(ws + OFF_Y1);

  hipLaunchKernelGGL(k_init, dim3(Cd), dim3(256), 0, stream, base, Db1, Sg, cst0, Yg0);
  hipLaunchKernelGGL(k_transpose_wcu, dim3(512), dim3(256), 0, stream, Wcu, WcuT);
  hipLaunchKernelGGL(k_prep_wcc, dim3(Cd), dim3(256), 0, stream,
                     Wcc, lcg, lcb, WccGT, GW, BW);
  hipLaunchKernelGGL(k_build_wc2, dim3(8192), dim3(256), 0, stream, Wc, Wc2);
  hipLaunchKernelGGL(k_prep_u, dim3(256), dim3(256), 0, stream, u, Ub);
  hipLaunchKernelGGL(k_build_cu, dim3(2048), dim3(256), 0, stream, Wu, bu, bc, Ub, CU);
  hipLaunchKernelGGL(k_prep_lu, dim3(256), dim3(256), 0, stream, u, WcuT, lug, lub, Lu);

  const unsigned short* Wc2u = (const unsigned short*)Wc2;
  const unsigned short* CUu  = (const unsigned short*)CU;

  for (int t = 0; t < Td; ++t) {
    const float* Dp = (t & 1) ? Db0 : Db1;
    float* Dc       = (t & 1) ? Db1 : Db0;
    const float* cp = (t & 1) ? cst1 : cst0;
    float* cc       = (t & 1) ? cst0 : cst1;
    const float* Yp = (t & 1) ? Yg1 : Yg0;
    float* Yc       = (t & 1) ? Yg0 : Yg1;
    hipLaunchKernelGGL(k_step, dim3(1024), dim3(256), 0, stream,
                       u, valid, Wg, bg, Lu, GW, BW, WccGT, Wc2u, CUu,
                       Dp, Dc, Sg, cp, cc, Yp, Yc, out, t);
  }
  // t=31 wrote Dcur=Db1, ccur=cst0
  hipLaunchKernelGGL(k_zfinal, dim3(128), dim3(256), 0, stream, Db1, cst0, out);
}

// Round 4
// 1120.173 us; speedup vs baseline: 1.3002x; 1.0109x over previous
//
#include <hip/hip_runtime.h>
#include <hip/hip_bf16.h>

namespace {

constexpr int Md = 512, Cd = 256, Bd = 8, Td = 32;
constexpr float kLam = 0.05f, kRho = 0.9f, kDlr = 0.03f;
constexpr float kEps = 1e-12f, kLnEps = 1e-5f;

typedef __attribute__((ext_vector_type(8))) short short8;
typedef __attribute__((ext_vector_type(4))) float float4v;

// ---- workspace layout (bytes) ----
constexpr size_t SZ_WC2   = (size_t)Cd * Cd * Md * 2;      // bf16 Wc2[c'][c][m]
constexpr size_t SZ_CU    = (size_t)Td * Bd * Cd * Md * 2; // bf16 CU[t*8+b][c][m]
constexpr size_t SZ_D     = (size_t)Bd * Cd * Md * 4;      // f32 D[b][c][m]
constexpr size_t SZ_S     = SZ_D;                          // f32 S[b][c][m]
constexpr size_t SZ_WCUT  = (size_t)Md * Cd * 4;
constexpr size_t SZ_WCCGT = (size_t)Cd * Cd * 4;           // f32 WccGT[i][c']
constexpr size_t SZ_LU    = (size_t)Td * Bd * Cd * 4;      // f32 Lu[t*8+b][c']
constexpr size_t SZ_UB    = (size_t)Td * Bd * Md * 2;      // bf16 Ub[n][d]
constexpr size_t SZ_CY    = (size_t)Bd * Cd * 4;           // f32 [b][c]

constexpr size_t OFF_WC2   = 0;
constexpr size_t OFF_CU    = OFF_WC2 + SZ_WC2;
constexpr size_t OFF_D0    = OFF_CU + SZ_CU;
constexpr size_t OFF_D1    = OFF_D0 + SZ_D;
constexpr size_t OFF_S     = OFF_D1 + SZ_D;
constexpr size_t OFF_WCUT  = OFF_S + SZ_S;
constexpr size_t OFF_WCCGT = OFF_WCUT + SZ_WCUT;
constexpr size_t OFF_GW    = OFF_WCCGT + SZ_WCCGT;
constexpr size_t OFF_BW    = OFF_GW + 1024;
constexpr size_t OFF_LU    = OFF_BW + 1024;
constexpr size_t OFF_UB    = OFF_LU + SZ_LU;
constexpr size_t OFF_C0    = OFF_UB + SZ_UB;
constexpr size_t OFF_C1    = OFF_C0 + SZ_CY;
constexpr size_t OFF_Y0    = OFF_C1 + SZ_CY;
constexpr size_t OFF_Y1    = OFF_Y0 + SZ_CY;
constexpr size_t OFF_ST0   = OFF_Y1 + SZ_CY;   // f32 [b][2] (sum, sumsq)
constexpr size_t OFF_ST1   = OFF_ST0 + 64;

__device__ __forceinline__ unsigned short f2bf(float x) {
  __hip_bfloat16 h = __float2bfloat16(x);
  return *reinterpret_cast<unsigned short*>(&h);
}

__device__ __forceinline__ float bf2float(unsigned short x) {
  unsigned int uu = ((unsigned int)x) << 16;
  return __uint_as_float(uu);
}

// ---- 256-thread block reductions (4 waves) ----
__device__ __forceinline__ float block_reduce_sum(float v, float* sbuf) {
  const int tid = threadIdx.x;
  #pragma unroll
  for (int o = 32; o > 0; o >>= 1) v += __shfl_down(v, o, 64);
  __syncthreads();
  if ((tid & 63) == 0) sbuf[tid >> 6] = v;
  __syncthreads();
  return sbuf[0] + sbuf[1] + sbuf[2] + sbuf[3];
}

__device__ __forceinline__ float2 block_reduce_sum2(float a, float b, float* sbuf) {
  const int tid = threadIdx.x;
  #pragma unroll
  for (int o = 32; o > 0; o >>= 1) {
    a += __shfl_down(a, o, 64);
    b += __shfl_down(b, o, 64);
  }
  __syncthreads();
  if ((tid & 63) == 0) { sbuf[tid >> 6] = a; sbuf[4 + (tid >> 6)] = b; }
  __syncthreads();
  return make_float2(sbuf[0] + sbuf[1] + sbuf[2] + sbuf[3],
                     sbuf[4] + sbuf[5] + sbuf[6] + sbuf[7]);
}

// red6: writes redf[0..23]; red2b: writes redf[24..31] (disjoint -> no extra sync)
__device__ __forceinline__ void red6_256(float& a, float& b, float& c,
                                         float& d, float& e, float& f,
                                         float* rf) {
  const int tid = threadIdx.x;
  #pragma unroll
  for (int o = 32; o > 0; o >>= 1) {
    a += __shfl_down(a, o, 64); b += __shfl_down(b, o, 64);
    c += __shfl_down(c, o, 64); d += __shfl_down(d, o, 64);
    e += __shfl_down(e, o, 64); f += __shfl_down(f, o, 64);
  }
  if ((tid & 63) == 0) {
    int w = tid >> 6;
    rf[w * 6 + 0] = a; rf[w * 6 + 1] = b; rf[w * 6 + 2] = c;
    rf[w * 6 + 3] = d; rf[w * 6 + 4] = e; rf[w * 6 + 5] = f;
  }
  __syncthreads();
  a = rf[0] + rf[6]  + rf[12] + rf[18];
  b = rf[1] + rf[7]  + rf[13] + rf[19];
  c = rf[2] + rf[8]  + rf[14] + rf[20];
  d = rf[3] + rf[9]  + rf[15] + rf[21];
  e = rf[4] + rf[10] + rf[16] + rf[22];
  f = rf[5] + rf[11] + rf[17] + rf[23];
}

__device__ __forceinline__ void red2_256b(float& a, float& b, float* rf) {
  const int tid = threadIdx.x;
  #pragma unroll
  for (int o = 32; o > 0; o >>= 1) {
    a += __shfl_down(a, o, 64);
    b += __shfl_down(b, o, 64);
  }
  if ((tid & 63) == 0) { int w = tid >> 6; rf[w * 2] = a; rf[w * 2 + 1] = b; }
  __syncthreads();
  a = rf[0] + rf[2] + rf[4] + rf[6];
  b = rf[1] + rf[3] + rf[5] + rf[7];
}

// ---- fused setup #1: init D/S/c/Y/ST + transpose Wcu + prep Wcc + prep u ----
// blocks [0,256)=init  [256,768)=transpose  [768,1024)=wcc  [1024,1280)=prep_u
__global__ __launch_bounds__(256) void k_setup1(
    const float* __restrict__ base, const float* __restrict__ Wcu,
    const float* __restrict__ Wcc, const float* __restrict__ lcg,
    const float* __restrict__ lcb, const float* __restrict__ u,
    float* __restrict__ D1, float* __restrict__ S,
    float* __restrict__ c0g, float* __restrict__ y0g,
    float* __restrict__ st0, float* __restrict__ st1,
    float* __restrict__ WcuT, float* __restrict__ WccGT,
    float* __restrict__ GW, float* __restrict__ BW,
    __hip_bfloat16* __restrict__ Ub) {
  __shared__ float red[8];
  const int tid = threadIdx.x;
  const int bid = blockIdx.x;
  if (bid < 256) {
    const int c = bid;
    float b0 = base[(size_t)tid * Cd + c];
    float b1 = base[(size_t)(tid + 256) * Cd + c];
    float ss = block_reduce_sum(b0 * b0 + b1 * b1, red);
    float rinv = 1.0f / fmaxf(sqrtf(ss), kEps);
    #pragma unroll
    for (int bb = 0; bb < Bd; ++bb) {
      size_t off = ((size_t)(bb * Cd + c)) * Md;
      D1[off + tid] = b0 * rinv;
      D1[off + tid + 256] = b1 * rinv;
    }
    size_t s0 = (size_t)c * 4096;
    #pragma unroll
    for (int k = 0; k < 16; ++k) S[s0 + k * 256 + tid] = 0.0f;
    if (c < Bd) { c0g[c * Cd + tid] = 0.0f; y0g[c * Cd + tid] = 0.0f; }
    if (c == 0 && tid < 16) { st0[tid] = 0.0f; st1[tid] = 0.0f; }
  } else if (bid < 768) {
    int g = (bid - 256) * 256 + tid;
    int d = g >> 8, c = g & 255;
    WcuT[g] = Wcu[(size_t)c * Md + d];
  } else if (bid < 1024) {
    const int cp = bid - 768;
    float wv = Wcc[(size_t)cp * Cd + tid];
    float g = lcg[tid], bb = lcb[tid];
    WccGT[(size_t)tid * Cd + cp] = g * wv;
    float2 ss = block_reduce_sum2(g * wv, bb * wv, red);
    if (tid == 0) { GW[cp] = ss.x; BW[cp] = ss.y; }
  } else {
    const int n = bid - 1024;
    const int t = n >> 3, b = n & 7;
    const float* src = u + ((size_t)(b * Td + t)) * Md;
    __hip_bfloat16* dst = Ub + (size_t)n * Md;
    dst[tid] = __float2bfloat16(src[tid]);
    dst[tid + 256] = __float2bfloat16(src[tid + 256]);
  }
}

// ---- fused setup #2: build Wc2 + build CU (MFMA) + prep Lu ----
// blocks [0,8192)=wc2  [8192,10240)=cu  [10240,10496)=lu
__global__ __launch_bounds__(256) void k_setup2(
    const float* __restrict__ Wc, const float* __restrict__ Wu,
    const float* __restrict__ bu, const float* __restrict__ bc,
    const __hip_bfloat16* __restrict__ Ub, const float* __restrict__ u,
    const float* __restrict__ WcuT, const float* __restrict__ lug,
    const float* __restrict__ lub,
    __hip_bfloat16* __restrict__ Wc2, __hip_bfloat16* __restrict__ CU,
    float* __restrict__ Lu) {
  __shared__ __align__(16) char sm[256 * 72 * 2];  // 36 KB union
  const int tid = threadIdx.x;
  const int bid = blockIdx.x;
  if (bid < 8192) {
    float (*tile)[65] = (float(*)[65])sm;
    const int ct = bid & 3;
    const int mt = (bid >> 2) & 7;
    const int c = bid >> 5;
    const int c0p = ct * 64, m0 = mt * 64;
    const int x = tid & 63, y = tid >> 6;
    #pragma unroll
    for (int i = 0; i < 16; ++i) {
      int mm = m0 + y + i * 4;
      tile[y + i * 4][x] = Wc[((size_t)(mm * Cd + c)) * Cd + c0p + x];
    }
    __syncthreads();
    #pragma unroll
    for (int i = 0; i < 16; ++i) {
      int cp = c0p + y + i * 4;
      Wc2[((size_t)(cp * Cd + c)) * Md + m0 + x] = __float2bfloat16(tile[x][y + i * 4]);
    }
  } else if (bid < 10240) {
    unsigned short* smem = (unsigned short*)sm;   // Bs: stride 40; Ct: stride 72
    const int bb = bid - 8192;
    const int c = bb >> 3;
    const int mt = bb & 7;
    const int w = tid >> 6;
    const int lane = tid & 63;
    const int l15 = lane & 15;
    const int quad = lane >> 4;

    float4v acc[16];
    #pragma unroll
    for (int j = 0; j < 16; ++j) acc[j] = (float4v){0.f, 0.f, 0.f, 0.f};

    const int mrow = mt * 64 + w * 16 + l15;
    const float* Arow = Wu + ((size_t)mrow * Cd + c) * Md;
    const unsigned short* ubp = (const unsigned short*)Ub + (size_t)tid * Md;

    for (int ch = 0; ch < 16; ++ch) {
      const int d0 = ch * 32;
      short8 s0 = *(const short8*)(ubp + d0);
      short8 s1 = *(const short8*)(ubp + d0 + 8);
      short8 s2 = *(const short8*)(ubp + d0 + 16);
      short8 s3 = *(const short8*)(ubp + d0 + 24);
      __syncthreads();
      *(short8*)&smem[tid * 40 + 0]  = s0;
      *(short8*)&smem[tid * 40 + 8]  = s1;
      *(short8*)&smem[tid * 40 + 16] = s2;
      *(short8*)&smem[tid * 40 + 24] = s3;
      float4 a0 = *(const float4*)(Arow + d0 + quad * 8);
      float4 a1 = *(const float4*)(Arow + d0 + quad * 8 + 4);
      short8 af;
      af[0] = (short)f2bf(a0.x); af[1] = (short)f2bf(a0.y);
      af[2] = (short)f2bf(a0.z); af[3] = (short)f2bf(a0.w);
      af[4] = (short)f2bf(a1.x); af[5] = (short)f2bf(a1.y);
      af[6] = (short)f2bf(a1.z); af[7] = (short)f2bf(a1.w);
      __syncthreads();
      #pragma unroll
      for (int j = 0; j < 16; ++j) {
        short8 bf = *(const short8*)&smem[(j * 16 + l15) * 40 + quad * 8];
        acc[j] = __builtin_amdgcn_mfma_f32_16x16x32_bf16(af, bf, acc[j], 0, 0, 0);
      }
    }

    float bias[4];
    #pragma unroll
    for (int r2 = 0; r2 < 4; ++r2) {
      int m = mt * 64 + w * 16 + quad * 4 + r2;
      bias[r2] = bu[(size_t)m * Cd + c] + bc[(size_t)m * Cd + c];
    }
    __syncthreads();
    #pragma unroll
    for (int j = 0; j < 16; ++j) {
      int tok = j * 16 + l15;
      int mlb = w * 16 + quad * 4;
      uint2 pk;
      pk.x = (unsigned)f2bf(acc[j][0] + bias[0]) |
             ((unsigned)f2bf(acc[j][1] + bias[1]) << 16);
      pk.y = (unsigned)f2bf(acc[j][2] + bias[2]) |
             ((unsigned)f2bf(acc[j][3] + bias[3]) << 16);
      *(uint2*)&smem[tok * 72 + mlb] = pk;
    }
    __syncthreads();
    #pragma unroll
    for (int rr = 0; rr < 8; ++rr) {
      int tok = (tid >> 3) + rr * 32;
      int ml0 = (tid & 7) * 8;
      short8 vv = *(const short8*)&smem[tok * 72 + ml0];
      *(short8*)((unsigned short*)CU + ((size_t)tok * Cd + c) * Md + mt * 64 + ml0) = vv;
    }
  } else {
    float* ln = (float*)sm;            // 512 floats
    float* red = ln + 512;             // 8 floats
    const int n = bid - 10240;         // n = t*8+b
    const int t = n >> 3, b = n & 7;
    const float* up = u + ((size_t)(b * Td + t)) * Md;
    float u0 = up[tid], u1 = up[tid + 256];
    float2 ss = block_reduce_sum2(u0 + u1, u0 * u0 + u1 * u1, red);
    float mu = ss.x * (1.0f / 512.0f);
    float var = ss.y * (1.0f / 512.0f) - mu * mu;
    float rsu = rsqrtf(var + kLnEps);
    ln[tid] = (u0 - mu) * rsu * lug[tid] + lub[tid];
    ln[tid + 256] = (u1 - mu) * rsu * lug[tid + 256] + lub[tid + 256];
    __syncthreads();
    float acc = 0.0f;
    #pragma unroll 8
    for (int i = 0; i < 512; ++i) acc = fmaf(ln[i], WcuT[(size_t)i * Cd + tid], acc);
    Lu[(size_t)n * Cd + tid] = acc;
  }
}

// ---- per-step kernel: 1024 blocks x 256 thr ----
// Block blk: b = blk>>7, j = blk&127. Thread roles:
//   tid as c-index (c-vector math: cv, Y, logits, gate c-term)
//   (grp = tid>>7, col = 2j+grp, mb = (tid&127)*4) for column work (float4 on m)
// LN-c stats carried incrementally in ST (no reduction). Top-8 on all 4 waves.
__global__ __launch_bounds__(256, 4) void k_step(
    const float* __restrict__ u, const float* __restrict__ valid,
    const float* __restrict__ Wg, const float* __restrict__ bg,
    const float* __restrict__ Lu, const float* __restrict__ GW,
    const float* __restrict__ BW, const float* __restrict__ WccGT,
    const unsigned short* __restrict__ Wc2, const unsigned short* __restrict__ CUb,
    const float* __restrict__ Dprev, float* __restrict__ Dcur,
    float* __restrict__ Sg,
    const float* __restrict__ cprev, float* __restrict__ ccur,
    const float* __restrict__ Yprev, float* __restrict__ Ycur,
    const float* __restrict__ STp, float* __restrict__ STc,
    float* __restrict__ out, int t) {
  __shared__ float scs[256];
  __shared__ float shs[256];
  __shared__ float zred[256];
  __shared__ float redf[32];

  const int tid = threadIdx.x;
  const int blk = blockIdx.x;
  const int b = blk >> 7;
  const int j = blk & 127;
  const int grp = tid >> 7;
  const int col = 2 * j + grp;
  const int mb = (tid & 127) * 4;

  // early independent loads (all pre-sync, latency overlapped)
  const float cv = cprev[b * Cd + tid];
  const float Yv = Yprev[b * Cd + tid];
  const float Ssum = STp[b * 2], Ssq = STp[b * 2 + 1];
  const float lu = Lu[((size_t)(t * Bd + b)) * Cd + tid];
  const float gw = GW[tid], bw = BW[tid];
  const float v = valid[b * Td + t];
  const float4 uu = *(const float4*)&u[((size_t)(b * Td + t)) * Md + mb];
  const float4 Sv = *(const float4*)&Sg[((size_t)(b * Cd + col)) * Md + mb];
  const float4 dp = *(const float4*)&Dprev[((size_t)(b * Cd + col)) * Md + mb];
  const ushort4 cuq =
      *(const ushort4*)&CUb[((size_t)((t * Bd + b) * Cd + col)) * Md + mb];

  const float lam_b = v * kRho + (1.f - v);
  const float mu_b  = v * (1.f - kRho);

  // z for step t-1 (16 designated blocks per b)
  float zacc = 0.f;
  const bool zb = (j < 16) && (t > 0);
  if (zb) {
    const int ml = tid & 31, cg2 = tid >> 5;
    const int m = j * 32 + ml;
    #pragma unroll 4
    for (int i = 0; i < 32; ++i) {
      int cc = cg2 * 32 + i;
      zacc = fmaf(Dprev[((size_t)(b * Cd + cc)) * Md + m], cprev[b * Cd + cc], zacc);
    }
  }

  // logits from carried LN stats (no reduction)
  const float muc = Ssum * (1.f / 256.f);
  const float rsc = rsqrtf(Ssq * (1.f / 256.f) - muc * muc + kLnEps);
  float lg = lu + rsc * (Yv - muc * gw) + bw;
  float sv = fmaxf(fabsf(lg) - kLam, 0.f);
  scs[tid] = sv;
  shs[tid] = (lg >= 0.f) ? sv : -sv;
  if (zb) zred[tid] = zacc;
  __syncthreads();

  if (zb && tid < 32) {
    float s = 0.f;
    #pragma unroll
    for (int g2 = 0; g2 < 8; ++g2) s += zred[g2 * 32 + tid];
    out[((size_t)(b * Td + (t - 1))) * Md + j * 32 + tid] = s;
  }

  // top-8 on ALL 4 waves (identical deterministic result -> registers, no sync)
  const int lane = tid & 63;
  float v4[4]; int i4[4];
  #pragma unroll
  for (int k = 0; k < 4; ++k) { i4[k] = lane * 4 + k; v4[k] = scs[lane * 4 + k]; }
  float av[8]; int ai[8];
  #pragma unroll
  for (int i = 0; i < 8; ++i) {
    float bv = v4[0]; int bi = i4[0];
    #pragma unroll
    for (int k = 1; k < 4; ++k)
      if (v4[k] > bv || (v4[k] == bv && i4[k] < bi)) { bv = v4[k]; bi = i4[k]; }
    #pragma unroll
    for (int o = 32; o > 0; o >>= 1) {
      float ov2 = __shfl_xor(bv, o, 64);
      int oi = __shfl_xor(bi, o, 64);
      if (ov2 > bv || (ov2 == bv && oi < bi)) { bv = ov2; bi = oi; }
    }
    ai[i] = bi; av[i] = shs[bi];
    if ((bi >> 2) == lane) v4[bi & 3] = -1.0f;
  }

  // c / Y update (tid = c-index role)
  float a_t = 0.f, a_col = 0.f;
  #pragma unroll
  for (int k = 0; k < 8; ++k) {
    if (ai[k] == tid) a_t = av[k];
    if (ai[k] == col) a_col = av[k];
  }
  float ct = lam_b * cv + mu_b * a_t;
  float yn = lam_b * Yv;
  #pragma unroll
  for (int k = 0; k < 8; ++k)
    yn = fmaf(mu_b * av[k], WccGT[(size_t)ai[k] * Cd + tid], yn);
  if (j == 0) { ccur[b * Cd + tid] = ct; Ycur[b * Cd + tid] = yn; }

  // u_hat -> r for this thread's 4 m
  float uh0 = 0.f, uh1 = 0.f, uh2 = 0.f, uh3 = 0.f;
  #pragma unroll
  for (int k = 0; k < 8; ++k) {
    float4 dq = *(const float4*)&Dprev[((size_t)(b * Cd + ai[k])) * Md + mb];
    uh0 = fmaf(av[k], dq.x, uh0); uh1 = fmaf(av[k], dq.y, uh1);
    uh2 = fmaf(av[k], dq.z, uh2); uh3 = fmaf(av[k], dq.w, uh3);
  }
  float r0 = uu.x - uh0, r1 = uu.y - uh1, r2 = uu.z - uh2, r3 = uu.w - uh3;

  // Wc2 gather -> S update -> cand
  float w0 = 0.f, w1 = 0.f, w2 = 0.f, w3 = 0.f;
  #pragma unroll
  for (int k = 0; k < 8; ++k) {
    ushort4 q = *(const ushort4*)&Wc2[((size_t)(ai[k] * Cd + col)) * Md + mb];
    float avk = av[k];
    w0 = fmaf(avk, bf2float(q.x), w0); w1 = fmaf(avk, bf2float(q.y), w1);
    w2 = fmaf(avk, bf2float(q.z), w2); w3 = fmaf(avk, bf2float(q.w), w3);
  }
  float sn0 = lam_b * Sv.x + mu_b * w0;
  float sn1 = lam_b * Sv.y + mu_b * w1;
  float sn2 = lam_b * Sv.z + mu_b * w2;
  float sn3 = lam_b * Sv.w + mu_b * w3;
  *(float4*)&Sg[((size_t)(b * Cd + col)) * Md + mb] =
      make_float4(sn0, sn1, sn2, sn3);

  float cn0 = bf2float(cuq.x) + sn0, cn1 = bf2float(cuq.y) + sn1;
  float cn2 = bf2float(cuq.z) + sn2, cn3 = bf2float(cuq.w) + sn3;
  float dl0 = fmaf(kDlr * a_col, r0, dp.x), dl1 = fmaf(kDlr * a_col, r1, dp.y);
  float dl2 = fmaf(kDlr * a_col, r2, dp.z), dl3 = fmaf(kDlr * a_col, r3, dp.w);

  // merged reduction: err2, gate-dot, cand-norms, dlocal-norms (per column)
  float candN = cn0 * cn0 + cn1 * cn1 + cn2 * cn2 + cn3 * cn3;
  float dlN = dl0 * dl0 + dl1 * dl1 + dl2 * dl2 + dl3 * dl3;
  float err2 = (grp == 0) ? (r0 * r0 + r1 * r1 + r2 * r2 + r3 * r3) : 0.f;
  const float4 wg4 = *(const float4*)&Wg[mb];
  float gpu = wg4.x * uu.x + wg4.y * uu.y + wg4.z * uu.z + wg4.w * uu.w;
  float gp = ((grp == 0) ? gpu : 0.f) + Wg[512 + tid] * ct;
  float na = grp ? 0.f : candN, nc = grp ? candN : 0.f;
  float nb = grp ? 0.f : dlN,   nd = grp ? dlN : 0.f;
  red6_256(err2, gp, na, nb, nc, nd, redf);

  float gate = 1.f / (1.f + expf(-(gp + Wg[768] * sqrtf(err2) + bg[0])));
  float ric = 1.f / fmaxf(sqrtf(grp ? nc : na), kEps);
  float rid = 1.f / fmaxf(sqrtf(grp ? nd : nb), kEps);
  float og = 1.f - gate;
  float e0 = og * dl0 * rid + gate * cn0 * ric;
  float e1 = og * dl1 * rid + gate * cn1 * ric;
  float e2v = og * dl2 * rid + gate * cn2 * ric;
  float e3 = og * dl3 * rid + gate * cn3 * ric;

  float qs = e0 * e0 + e1 * e1 + e2v * e2v + e3 * e3;
  float qa = grp ? 0.f : qs, qb = grp ? qs : 0.f;
  red2_256b(qa, qb, redf + 24);
  float rie = 1.f / fmaxf(sqrtf(grp ? qb : qa), kEps);

  float ov = 1.f - v;
  float dn0 = v * (e0 * rie) + ov * dp.x;
  float dn1 = v * (e1 * rie) + ov * dp.y;
  float dn2 = v * (e2v * rie) + ov * dp.z;
  float dn3 = v * (e3 * rie) + ov * dp.w;
  *(float4*)&Dcur[((size_t)(b * Cd + col)) * Md + mb] =
      make_float4(dn0, dn1, dn2, dn3);

  // next-step LN-c stats (incremental; j==0 tid==0)
  if (j == 0 && tid == 0) {
    float sA = 0.f, sCA = 0.f, sA2 = 0.f;
    #pragma unroll
    for (int k = 0; k < 8; ++k) {
      float cpk = cprev[b * Cd + ai[k]];
      sA += av[k];
      sCA = fmaf(cpk, av[k], sCA);
      sA2 = fmaf(av[k], av[k], sA2);
    }
    STc[b * 2] = lam_b * Ssum + mu_b * sA;
    STc[b * 2 + 1] = lam_b * lam_b * Ssq + 2.f * lam_b * mu_b * sCA
                     + mu_b * mu_b * sA2;
  }
}

// ---- final z for t = T-1: 128 blocks = (b, j) ----
__global__ __launch_bounds__(256) void k_zfinal(const float* __restrict__ Dlast,
                                                const float* __restrict__ clast,
                                                float* __restrict__ out) {
  __shared__ float cs[256];
  __shared__ float zred[256];
  const int tid = threadIdx.x;
  const int b = blockIdx.x >> 4;
  const int j = blockIdx.x & 15;
  cs[tid] = clast[b * Cd + tid];
  __syncthreads();
  const int ml = tid & 31, cgp = tid >> 5;
  const int m = j * 32 + ml;
  float acc = 0.f;
  #pragma unroll 4
  for (int i = 0; i < 32; ++i) {
    int cc = cgp * 32 + i;
    acc = fmaf(Dlast[((size_t)(b * Cd + cc)) * Md + m], cs[cc], acc);
  }
  zred[tid] = acc;
  __syncthreads();
  if (tid < 32) {
    float s = 0.f;
    #pragma unroll
    for (int g2 = 0; g2 < 8; ++g2) s += zred[g2 * 32 + tid];
    out[((size_t)(b * Td + (Td - 1))) * Md + j * 32 + tid] = s;
  }
}

}  // namespace

extern "C" void kernel_launch(void* const* d_in, const int* in_sizes, int n_in,
                              void* d_out, int out_size, void* d_ws, size_t ws_size,
                              hipStream_t stream) {
  (void)in_sizes; (void)n_in; (void)out_size; (void)ws_size;
  const float* u     = (const float*)d_in[0];
  const float* valid = (const float*)d_in[1];
  const float* base  = (const float*)d_in[2];
  const float* Wcu   = (const float*)d_in[3];
  const float* Wcc   = (const float*)d_in[4];
  const float* Wu    = (const float*)d_in[5];
  const float* bu    = (const float*)d_in[6];
  const float* Wc    = (const float*)d_in[7];
  const float* bc    = (const float*)d_in[8];
  const float* Wg    = (const float*)d_in[9];
  const float* bg    = (const float*)d_in[10];
  const float* lug   = (const float*)d_in[11];
  const float* lub   = (const float*)d_in[12];
  const float* lcg   = (const float*)d_in[13];
  const float* lcb   = (const float*)d_in[14];
  float* out = (float*)d_out;
  char* ws = (char*)d_ws;

  __hip_bfloat16* Wc2 = (__hip_bfloat16*)(ws + OFF_WC2);
  __hip_bfloat16* CU  = (__hip_bfloat16*)(ws + OFF_CU);
  float* Db0   = (float*)(ws + OFF_D0);
  float* Db1   = (float*)(ws + OFF_D1);
  float* Sg    = (float*)(ws + OFF_S);
  float* WcuT  = (float*)(ws + OFF_WCUT);
  float* WccGT = (float*)(ws + OFF_WCCGT);
  float* GW    = (float*)(ws + OFF_GW);
  float* BW    = (float*)(ws + OFF_BW);
  float* Lu    = (float*)(ws + OFF_LU);
  __hip_bfloat16* Ub = (__hip_bfloat16*)(ws + OFF_UB);
  float* cst0  = (float*)(ws + OFF_C0);
  float* cst1  = (float*)(ws + OFF_C1);
  float* Yg0   = (float*)(ws + OFF_Y0);
  float* Yg1   = (float*)(ws + OFF_Y1);
  float* ST0   = (float*)(ws + OFF_ST0);
  float* ST1   = (float*)(ws + OFF_ST1);

  hipLaunchKernelGGL(k_setup1, dim3(1280), dim3(256), 0, stream,
                     base, Wcu, Wcc, lcg, lcb, u,
                     Db1, Sg, cst0, Yg0, ST0, ST1, WcuT, WccGT, GW, BW, Ub);
  hipLaunchKernelGGL(k_setup2, dim3(10496), dim3(256), 0, stream,
                     Wc, Wu, bu, bc, Ub, u, WcuT, lug, lub, Wc2, CU, Lu);

  const unsigned short* Wc2u = (const unsigned short*)Wc2;
  const unsigned short* CUu  = (const unsigned short*)CU;

  for (int t = 0; t < Td; ++t) {
    const float* Dp = (t & 1) ? Db0 : Db1;
    float* Dc       = (t & 1) ? Db1 : Db0;
    const float* cp = (t & 1) ? cst1 : cst0;
    float* cc       = (t & 1) ? cst0 : cst1;
    const float* Yp = (t & 1) ? Yg1 : Yg0;
    float* Yc       = (t & 1) ? Yg0 : Yg1;
    const float* Sp = (t & 1) ? ST1 : ST0;
    float* Sc       = (t & 1) ? ST0 : ST1;
    hipLaunchKernelGGL(k_step, dim3(1024), dim3(256), 0, stream,
                       u, valid, Wg, bg, Lu, GW, BW, WccGT, Wc2u, CUu,
                       Dp, Dc, Sg, cp, cc, Yp, Yc, Sp, Sc, out, t);
  }
  // t=31 wrote Dcur=Db1, ccur=cst0
  hipLaunchKernelGGL(k_zfinal, dim3(128), dim3(256), 0, stream, Db1, cst0, out);
}